// Round 15
// baseline (108.065 us; speedup 1.0000x reference)
//
#include <hip/hip_runtime.h>
#include <hip/hip_bf16.h>

typedef __bf16 bf16x8 __attribute__((ext_vector_type(8)));
typedef __bf16 bf16x4 __attribute__((ext_vector_type(4)));
typedef float  f32x4  __attribute__((ext_vector_type(4)));
typedef _Float16 f16x4 __attribute__((ext_vector_type(4)));

#define NB 4
#define SEQ 4096
#define DIM 128

static __device__ __forceinline__ unsigned int bf16bits(__bf16 h) {
    return (unsigned int)__builtin_bit_cast(unsigned short, h);
}

// global -> LDS direct copy, 16B per lane; LDS dest is wave-uniform base,
// HW writes lane i at base + i*16 (m104). Global src is per-lane (m173).
#define GLOAD_LDS16(g, s) __builtin_amdgcn_global_load_lds(                    \
    (const __attribute__((address_space(1))) void*)(g),                        \
    (__attribute__((address_space(3))) void*)(s), 16, 0, 0)

// ---------------------------------------------------------------------------
// Kernel 0: W fp32 -> (Wh, Wl) bf16 split pair.  Wh = bf16(w), Wl = bf16(w-Wh)
// ---------------------------------------------------------------------------
__global__ __launch_bounds__(256) void wconv(
    const float* __restrict__ Wq, const float* __restrict__ Wk,
    const float* __restrict__ Wv,
    __bf16* __restrict__ Wh, __bf16* __restrict__ Wl)
{
    int idx = blockIdx.x * 256 + threadIdx.x;     // float4 index, 12288 total
    int which = idx >> 12;                        // 4096 float4 per matrix
    int off = (idx & 4095) * 4;
    const float* W = which == 0 ? Wq : (which == 1 ? Wk : Wv);
    float4 v = *(const float4*)(W + off);
    bf16x4 h, lo;
    h[0] = (__bf16)v.x; h[1] = (__bf16)v.y; h[2] = (__bf16)v.z; h[3] = (__bf16)v.w;
    lo[0] = (__bf16)(v.x - (float)h[0]);
    lo[1] = (__bf16)(v.y - (float)h[1]);
    lo[2] = (__bf16)(v.z - (float)h[2]);
    lo[3] = (__bf16)(v.w - (float)h[3]);
    *(bf16x4*)(Wh + which * 16384 + off) = h;
    *(bf16x4*)(Wl + which * 16384 + off) = lo;
}

// ---------------------------------------------------------------------------
// Kernel 1 (R15): FUSED QKV projection, ct-split across blockIdx.y, with
// FULL W REGISTER PRELOAD: all 24 W fragments (3ct x 4kb x {h,l} = 96 VGPR)
// issued upfront -> kb loop has NO global loads on the critical path.
// grid (256 row-tiles of 64, 2 ct-halves of 12), block 256.
// 3-term split-bf16: y = xh@Wh + xh@Wl + xl@Wh.
// ---------------------------------------------------------------------------
union QkvSh {
    float  xs[64][132];              // 33.8 KB, padded: conflict-free b128
    __bf16 vbuf[64][200];            // 25.6 KB: 12 cts x 16 cols + 8 pad
};

__global__ __launch_bounds__(256) void qkv_proj3(
    const float* __restrict__ x,
    const __bf16* __restrict__ Whg, const __bf16* __restrict__ Wlg,
    const float* __restrict__ bq, const float* __restrict__ bk,
    const float* __restrict__ bv,
    __bf16* __restrict__ Q, __bf16* __restrict__ K, __bf16* __restrict__ Vt)
{
    __shared__ QkvSh sh;
    const int t  = threadIdx.x;
    const int w  = t >> 6, l = t & 63, lg = l >> 4, ll = l & 15;
    const int rt = blockIdx.x;
    const int ct0 = blockIdx.y * 12;           // 0 or 12

    // preload ALL W fragments (issued as 24 independent b128 loads)
    bf16x8 whr[3][4], wlr[3][4];
    #pragma unroll
    for (int i = 0; i < 3; ++i) {
        int gct = ct0 + w * 3 + i;
        const __bf16* wb = Whg + (gct >> 3) * 16384 + ((gct & 7) * 16 + ll) * 128 + lg * 8;
        const __bf16* lb = Wlg + (gct >> 3) * 16384 + ((gct & 7) * 16 + ll) * 128 + lg * 8;
        #pragma unroll
        for (int kb = 0; kb < 4; ++kb) {
            whr[i][kb] = *(const bf16x8*)(wb + kb * 32);
            wlr[i][kb] = *(const bf16x8*)(lb + kb * 32);
        }
    }

    // stage x tile 64x128 -> padded LDS (2048 float4)
    {
        const float4* xsrc = (const float4*)(x + rt * 64 * 128);
        #pragma unroll
        for (int ii = 0; ii < 8; ++ii) {
            int u = t + ii * 256;              // row = u>>5, c4 = u&31
            float4 v4 = xsrc[u];
            *(float4*)&sh.xs[u >> 5][(u & 31) * 4] = v4;
        }
    }
    __syncthreads();

    float bfr[3];
    #pragma unroll
    for (int i = 0; i < 3; ++i) {
        int gct = ct0 + w * 3 + i;
        const float* bias = gct < 8 ? bq : (gct < 16 ? bk : bv);
        bfr[i] = bias[(gct & 7) * 16 + ll];
    }

    f32x4 acc[3][4];
    #pragma unroll
    for (int i = 0; i < 3; ++i)
        #pragma unroll
        for (int rf = 0; rf < 4; ++rf) acc[i][rf] = (f32x4){0.f, 0.f, 0.f, 0.f};

    #pragma unroll 1
    for (int kb = 0; kb < 4; ++kb) {
        bf16x8 xh[4], xl[4];
        #pragma unroll
        for (int rf = 0; rf < 4; ++rf) {
            float4 xa = *(const float4*)&sh.xs[rf * 16 + ll][kb * 32 + lg * 8];
            float4 xb = *(const float4*)&sh.xs[rf * 16 + ll][kb * 32 + lg * 8 + 4];
            float xv[8] = {xa.x, xa.y, xa.z, xa.w, xb.x, xb.y, xb.z, xb.w};
            #pragma unroll
            for (int j = 0; j < 8; ++j) {
                __bf16 h = (__bf16)xv[j];
                xh[rf][j] = h;
                xl[rf][j] = (__bf16)(xv[j] - (float)h);
            }
        }
        #pragma unroll
        for (int i = 0; i < 3; ++i) {
            #pragma unroll
            for (int rf = 0; rf < 4; ++rf) {
                acc[i][rf] = __builtin_amdgcn_mfma_f32_16x16x32_bf16(xh[rf], whr[i][kb], acc[i][rf], 0, 0, 0);
                acc[i][rf] = __builtin_amdgcn_mfma_f32_16x16x32_bf16(xh[rf], wlr[i][kb], acc[i][rf], 0, 0, 0);
                acc[i][rf] = __builtin_amdgcn_mfma_f32_16x16x32_bf16(xl[rf], whr[i][kb], acc[i][rf], 0, 0, 0);
            }
        }
    }

    __syncthreads();     // xs dead; overlay vbuf
    const float qscale = 0.08838834764831845f;  // 1/sqrt(128)
    #pragma unroll
    for (int i = 0; i < 3; ++i) {
        int gct = ct0 + w * 3 + i;
        float scale = (gct < 8) ? qscale : 1.0f;
        int lct = w * 3 + i;
        #pragma unroll
        for (int rf = 0; rf < 4; ++rf)
            #pragma unroll
            for (int r = 0; r < 4; ++r)
                sh.vbuf[rf * 16 + lg * 4 + r][lct * 16 + ll] =
                    (__bf16)((acc[i][rf][r] + bfr[i]) * scale);
    }
    __syncthreads();

    // coalesced stores per ct-chunk: Q,K row-major; V transposed
    #pragma unroll 1
    for (int lct = 0; lct < 12; ++lct) {
        int gct = ct0 + lct;
        if (gct < 16) {
            // 64 rows x 16 cols; thread t: row t>>2, 4-col chunk t&3
            int row = t >> 2, c = (t & 3) * 4;
            __bf16* base = (gct < 8 ? Q : K);
            bf16x4 v4 = *(const bf16x4*)&sh.vbuf[row][lct * 16 + c];
            *(bf16x4*)(base + (rt * 64 + row) * 128 + (gct & 7) * 16 + c) = v4;
        } else {
            // V transposed: 16 channels x 64 seq; thread t: ch t>>4, 4-seq t&15
            int e = (gct - 16) * 16 + (t >> 4);
            int s0 = (t & 15) * 4;
            int bb = rt >> 6, sb = (rt & 63) * 64 + s0;
            bf16x4 v4;
            #pragma unroll
            for (int j = 0; j < 4; ++j) v4[j] = sh.vbuf[s0 + j][lct * 16 + (t >> 4)];
            *(bf16x4*)(Vt + bb * (128 * 4096) + e * 4096 + sb) = v4;
        }
    }
}

// ---------------------------------------------------------------------------
// Kernel 2: flash attention partial (R12 anchor; only change: Op in fp16).
// DOUBLE-BUFFERED K/V, issue-early staging, one vmcnt(0)+barrier per iter.
// 2x q-row register blocking; swapped QK^T; lane-scalar softmax.
// ---------------------------------------------------------------------------
__global__ __launch_bounds__(256, 2) void attn_fwd(
    const __bf16* __restrict__ Qg,
    const __bf16* __restrict__ Kg,
    const __bf16* __restrict__ Vt,
    _Float16* __restrict__ Op, float* __restrict__ m_p, float* __restrict__ l_p,
    int kv_len)
{
    __shared__ __align__(16) __bf16 Kl[2][64][128];     // [buf][key][d], swizzled units
    __shared__ __align__(16) __bf16 Vl[2][128][64];     // [buf][d][key], swizzled
    __shared__ __align__(16) __bf16 PlT[4][2][16][64];  // [wave][h][qrow][key]

    const int t  = threadIdx.x;
    const int w  = t >> 6;
    const int l  = t & 63, lg = l >> 4, ll = l & 15;
    const int sK = ll & 7;

    // ---- XCD-aware bijective swizzle (nwg = 128*nsplit, divisible by 8) ----
    const int nwg = gridDim.x * gridDim.y;
    const int lin = blockIdx.x + gridDim.x * blockIdx.y;
    const int chunk = nwg >> 3;
    const int v = (lin & 7) * chunk + (lin >> 3);
    const int qt = v & 31;
    const int b  = (v >> 5) & 3;
    const int s  = v >> 7;

    const int qrow0 = qt * 128 + w * 32;

    // Q fragments for both 16-row groups (scale folded at qkv)
    bf16x8 qa[2][4];
    #pragma unroll
    for (int h = 0; h < 2; ++h) {
        const __bf16* qb = Qg + (b * 4096 + qrow0 + h * 16 + ll) * 128 + lg * 8;
        #pragma unroll
        for (int kb = 0; kb < 4; ++kb) qa[h][kb] = *(const bf16x8*)(qb + kb * 32);
    }

    f32x4 o[2][8];
    #pragma unroll
    for (int h = 0; h < 2; ++h)
        #pragma unroll
        for (int dt = 0; dt < 8; ++dt) o[h][dt] = (f32x4){0.f, 0.f, 0.f, 0.f};
    float m[2] = {-1e30f, -1e30f}, lsum[2] = {0.f, 0.f};

    const __bf16* kbase = Kg + ((long)b * 4096 + s * kv_len) * 128;
    const __bf16* vbase = Vt + (long)b * 128 * 4096 + s * kv_len;

    // per-lane pre-swizzled source offsets; LDS dest stays linear
    int ksrc_off[4], vsrc_off[4];
    #pragma unroll
    for (int ii = 0; ii < 4; ++ii) {
        int u = w * 256 + ii * 64 + l;               // 16B unit index, [0,1024)
        int kr = u >> 4, kc = u & 15;
        ksrc_off[ii] = kr * 128 + ((kc ^ (kr & 7)) * 8);
        int vr = u >> 3, vc = u & 7;
        vsrc_off[ii] = vr * 4096 + ((vc ^ (vr & 7)) * 8);
    }

    #define STAGE(kv, bp)                                                      \
    do {                                                                       \
        _Pragma("unroll")                                                      \
        for (int ii = 0; ii < 4; ++ii)                                         \
            GLOAD_LDS16(kbase + (long)(kv) * 128 + ksrc_off[ii],               \
                        (char*)&Kl[bp][0][0] + (w * 256 + ii * 64) * 16);      \
        _Pragma("unroll")                                                      \
        for (int ii = 0; ii < 4; ++ii)                                         \
            GLOAD_LDS16(vbase + (kv) + vsrc_off[ii],                           \
                        (char*)&Vl[bp][0][0] + (w * 256 + ii * 64) * 16);      \
    } while (0)

    STAGE(0, 0);
    asm volatile("s_waitcnt vmcnt(0)" ::: "memory");
    __syncthreads();

    const int nit = kv_len >> 6;
    int p = 0;
    for (int it = 0; it < nit; ++it) {
        // issue next tile into the other buffer NOW; wait at iter end.
        // (prior barrier => all waves done reading buf p^1)
        if (it + 1 < nit) STAGE((it + 1) * 64, p ^ 1);

        // QK^T swapped: f[h][nt][r] = S[key = nt*16+lg*4+r][qrow(h) = ll]
        f32x4 f[2][4];
        #pragma unroll
        for (int h = 0; h < 2; ++h)
            #pragma unroll
            for (int nt = 0; nt < 4; ++nt) f[h][nt] = (f32x4){0.f, 0.f, 0.f, 0.f};
        #pragma unroll
        for (int nt = 0; nt < 4; ++nt) {
            #pragma unroll
            for (int kb = 0; kb < 4; ++kb) {
                bf16x8 kf = *(const bf16x8*)&Kl[p][nt * 16 + ll][((kb * 4 + lg) ^ sK) * 8];
                f[0][nt] = __builtin_amdgcn_mfma_f32_16x16x32_bf16(kf, qa[0][kb], f[0][nt], 0, 0, 0);
                f[1][nt] = __builtin_amdgcn_mfma_f32_16x16x32_bf16(kf, qa[1][kb], f[1][nt], 0, 0, 0);
            }
        }

        // softmax per row-group (lane scalar state for q-row ll)
        float alpha[2];
        #pragma unroll
        for (int h = 0; h < 2; ++h) {
            float mx = f[h][0][0];
            #pragma unroll
            for (int nt = 0; nt < 4; ++nt)
                #pragma unroll
                for (int r = 0; r < 4; ++r) mx = fmaxf(mx, f[h][nt][r]);
            mx = fmaxf(mx, __shfl_xor(mx, 16, 64));
            mx = fmaxf(mx, __shfl_xor(mx, 32, 64));
            float mnew = fmaxf(m[h], mx);
            alpha[h] = __expf(m[h] - mnew);
            float rsum = 0.f;
            #pragma unroll
            for (int nt = 0; nt < 4; ++nt) {
                __bf16 pb[4];
                #pragma unroll
                for (int r = 0; r < 4; ++r) {
                    float e = __expf(f[h][nt][r] - mnew);
                    pb[r] = (__bf16)e;
                    rsum += (float)pb[r];   // sum bf16-rounded P: normalization cancels
                }
                uint2 u2;
                u2.x = bf16bits(pb[0]) | (bf16bits(pb[1]) << 16);
                u2.y = bf16bits(pb[2]) | (bf16bits(pb[3]) << 16);
                *(uint2*)&PlT[w][h][ll][((nt * 4 + lg) ^ (sK << 1)) * 4] = u2;
            }
            rsum += __shfl_xor(rsum, 16, 64);
            rsum += __shfl_xor(rsum, 32, 64);
            lsum[h] = lsum[h] * alpha[h] + rsum;
            m[h] = mnew;
        }
        asm volatile("s_waitcnt lgkmcnt(0)" ::: "memory");
        __builtin_amdgcn_sched_barrier(0);

        // rescale O (alpha for q-rows lg*4+r held at lanes lg*4+r)
        #pragma unroll
        for (int h = 0; h < 2; ++h) {
            float arow[4];
            #pragma unroll
            for (int r = 0; r < 4; ++r) arow[r] = __shfl(alpha[h], lg * 4 + r, 64);
            #pragma unroll
            for (int dt = 0; dt < 8; ++dt)
                #pragma unroll
                for (int r = 0; r < 4; ++r) o[h][dt][r] *= arow[r];
        }

        // PV: each V fragment feeds both row-groups
        #pragma unroll
        for (int kc = 0; kc < 2; ++kc) {
            bf16x8 pa0 = *(const bf16x8*)&PlT[w][0][ll][((kc * 4 + lg) ^ sK) * 8];
            bf16x8 pa1 = *(const bf16x8*)&PlT[w][1][ll][((kc * 4 + lg) ^ sK) * 8];
            #pragma unroll
            for (int dt = 0; dt < 8; ++dt) {
                bf16x8 vb = *(const bf16x8*)&Vl[p][dt * 16 + ll][((kc * 4 + lg) ^ sK) * 8];
                o[0][dt] = __builtin_amdgcn_mfma_f32_16x16x32_bf16(pa0, vb, o[0][dt], 0, 0, 0);
                o[1][dt] = __builtin_amdgcn_mfma_f32_16x16x32_bf16(pa1, vb, o[1][dt], 0, 0, 0);
            }
        }

        // next tile's DMA done? then flip. ONE barrier per iteration.
        asm volatile("s_waitcnt vmcnt(0)" ::: "memory");
        __syncthreads();
        p ^= 1;
    }
    #undef STAGE

    // epilogue: unnormalized partial O (fp16) + per-row (m, lsum)
    #pragma unroll
    for (int h = 0; h < 2; ++h) {
        long rowbase = (long)s * (NB * SEQ) + b * 4096 + qrow0 + h * 16;
        _Float16* op = Op + rowbase * 128;
        #pragma unroll
        for (int r = 0; r < 4; ++r)
            #pragma unroll
            for (int dt = 0; dt < 8; ++dt)
                op[(lg * 4 + r) * 128 + dt * 16 + ll] = (_Float16)o[h][dt][r];
        if (lg == 0) {
            m_p[rowbase + ll] = m[h];
            l_p[rowbase + ll] = lsum[h];
        }
    }
}

// ---------------------------------------------------------------------------
// Kernel 3: merge split-K partials (Op fp16).  grid 256 x 256 thr.
// ---------------------------------------------------------------------------
__global__ __launch_bounds__(256) void attn_merge(
    const _Float16* __restrict__ Op, const float* __restrict__ m_p,
    const float* __restrict__ l_p, float* __restrict__ out, int nsplit)
{
    const int t = threadIdx.x;
    const int base_row = blockIdx.x * 64;
    #pragma unroll 1
    for (int k = 0; k < 8; ++k) {
        int u = t + k * 256;                 // float4 unit within 64x128 tile
        int row = base_row + (u >> 5);
        int dq = u & 31;
        float M = -1e30f;
        for (int sp = 0; sp < nsplit; ++sp)
            M = fmaxf(M, m_p[(long)sp * (NB * SEQ) + row]);
        float L = 0.f;
        float4 acc = {0.f, 0.f, 0.f, 0.f};
        for (int sp = 0; sp < nsplit; ++sp) {
            long rb2 = (long)sp * (NB * SEQ) + row;
            float a = __expf(m_p[rb2] - M);
            L += l_p[rb2] * a;
            f16x4 vv = *(const f16x4*)(Op + rb2 * 128 + dq * 4);
            acc.x += (float)vv[0] * a; acc.y += (float)vv[1] * a;
            acc.z += (float)vv[2] * a; acc.w += (float)vv[3] * a;
        }
        float inv = 1.f / L;
        float4 r4 = {acc.x * inv, acc.y * inv, acc.z * inv, acc.w * inv};
        *(float4*)(out + (long)row * 128 + dq * 4) = r4;
    }
}

extern "C" void kernel_launch(void* const* d_in, const int* in_sizes, int n_in,
                              void* d_out, int out_size, void* d_ws, size_t ws_size,
                              hipStream_t stream) {
    (void)in_sizes; (void)n_in; (void)out_size;
    const float* x  = (const float*)d_in[0];
    const float* Wq = (const float*)d_in[1];
    const float* bq = (const float*)d_in[2];
    const float* Wk = (const float*)d_in[3];
    const float* bk = (const float*)d_in[4];
    const float* Wv = (const float*)d_in[5];
    const float* bv = (const float*)d_in[6];
    float* out = (float*)d_out;

    const size_t qkv_elems = (size_t)NB * SEQ * DIM;          // 2 MB elems
    char* p = (char*)d_ws;
    __bf16* Q  = (__bf16*)p;        p += qkv_elems * 2;       // 4 MB
    __bf16* K  = (__bf16*)p;        p += qkv_elems * 2;       // 4 MB
    __bf16* Vt = (__bf16*)p;        p += qkv_elems * 2;       // 4 MB
    __bf16* Wh = (__bf16*)p;        p += 3 * DIM * DIM * 2;   // 96 KB
    __bf16* Wl = (__bf16*)p;        p += 3 * DIM * DIM * 2;   // 96 KB
    size_t used = (size_t)(p - (char*)d_ws);

    // partials: per split 4 MB O (fp16) + 64 KB m + 64 KB l
    const size_t per_split = (size_t)NB * SEQ * DIM * 2 + 2 * (size_t)NB * SEQ * 4;
    int nsplit = 4;
    while (nsplit > 1 && used + (size_t)nsplit * per_split > ws_size) nsplit >>= 1;

    _Float16* Op = (_Float16*)p;                 p += (size_t)nsplit * NB * SEQ * DIM * 2;
    float* m_p = (float*)p;                      p += (size_t)nsplit * NB * SEQ * 4;
    float* l_p = (float*)p;

    wconv<<<48, 256, 0, stream>>>(Wq, Wk, Wv, Wh, Wl);
    dim3 g1(256, 2);
    qkv_proj3<<<g1, 256, 0, stream>>>(x, Wh, Wl, bq, bk, bv, Q, K, Vt);
    dim3 g2(128, nsplit);
    attn_fwd<<<g2, 256, 0, stream>>>(Q, K, Vt, Op, m_p, l_p, SEQ / nsplit);
    attn_merge<<<256, 256, 0, stream>>>(Op, m_p, l_p, out, nsplit);
}

// Round 16
// 93.432 us; speedup vs baseline: 1.1566x; 1.1566x over previous
//
#include <hip/hip_runtime.h>
#include <hip/hip_bf16.h>

typedef __bf16 bf16x8 __attribute__((ext_vector_type(8)));
typedef __bf16 bf16x4 __attribute__((ext_vector_type(4)));
typedef float  f32x4  __attribute__((ext_vector_type(4)));
typedef _Float16 f16x4 __attribute__((ext_vector_type(4)));

#define NB 4
#define SEQ 4096
#define DIM 128

static __device__ __forceinline__ unsigned int bf16bits(__bf16 h) {
    return (unsigned int)__builtin_bit_cast(unsigned short, h);
}

// global -> LDS direct copy, 16B per lane; LDS dest is wave-uniform base,
// HW writes lane i at base + i*16 (m104). Global src is per-lane (m173).
#define GLOAD_LDS16(g, s) __builtin_amdgcn_global_load_lds(                    \
    (const __attribute__((address_space(1))) void*)(g),                        \
    (__attribute__((address_space(3))) void*)(s), 16, 0, 0)

// ---------------------------------------------------------------------------
// Kernel 0: W fp32 -> (Wh, Wl) bf16 split pair.  Wh = bf16(w), Wl = bf16(w-Wh)
// ---------------------------------------------------------------------------
__global__ __launch_bounds__(256) void wconv(
    const float* __restrict__ Wq, const float* __restrict__ Wk,
    const float* __restrict__ Wv,
    __bf16* __restrict__ Wh, __bf16* __restrict__ Wl)
{
    int idx = blockIdx.x * 256 + threadIdx.x;     // float4 index, 12288 total
    int which = idx >> 12;                        // 4096 float4 per matrix
    int off = (idx & 4095) * 4;
    const float* W = which == 0 ? Wq : (which == 1 ? Wk : Wv);
    float4 v = *(const float4*)(W + off);
    bf16x4 h, lo;
    h[0] = (__bf16)v.x; h[1] = (__bf16)v.y; h[2] = (__bf16)v.z; h[3] = (__bf16)v.w;
    lo[0] = (__bf16)(v.x - (float)h[0]);
    lo[1] = (__bf16)(v.y - (float)h[1]);
    lo[2] = (__bf16)(v.z - (float)h[2]);
    lo[3] = (__bf16)(v.w - (float)h[3]);
    *(bf16x4*)(Wh + which * 16384 + off) = h;
    *(bf16x4*)(Wl + which * 16384 + off) = lo;
}

// ---------------------------------------------------------------------------
// Kernel 1 (R14 verbatim): FUSED QKV projection, ct-split across blockIdx.y.
// grid (256 row-tiles of 64, 2 ct-halves of 12), block 256. In-loop W loads
// (R15's full W-preload spilled — reverted). 34 KB LDS -> 2 blocks/CU.
// 3-term split-bf16: y = xh@Wh + xh@Wl + xl@Wh.
// ---------------------------------------------------------------------------
union QkvSh {
    float  xs[64][132];              // 33.8 KB, padded: conflict-free b128
    __bf16 vbuf[64][200];            // 25.6 KB: 12 cts x 16 cols + 8 pad
};

__global__ __launch_bounds__(256) void qkv_proj3(
    const float* __restrict__ x,
    const __bf16* __restrict__ Whg, const __bf16* __restrict__ Wlg,
    const float* __restrict__ bq, const float* __restrict__ bk,
    const float* __restrict__ bv,
    __bf16* __restrict__ Q, __bf16* __restrict__ K, __bf16* __restrict__ Vt)
{
    __shared__ QkvSh sh;
    const int t  = threadIdx.x;
    const int w  = t >> 6, l = t & 63, lg = l >> 4, ll = l & 15;
    const int rt = blockIdx.x;
    const int ct0 = blockIdx.y * 12;           // 0 or 12

    // stage x tile 64x128 -> padded LDS (2048 float4)
    {
        const float4* xsrc = (const float4*)(x + rt * 64 * 128);
        #pragma unroll
        for (int ii = 0; ii < 8; ++ii) {
            int u = t + ii * 256;              // row = u>>5, c4 = u&31
            float4 v4 = xsrc[u];
            *(float4*)&sh.xs[u >> 5][(u & 31) * 4] = v4;
        }
    }
    __syncthreads();

    float bfr[3];
    #pragma unroll
    for (int i = 0; i < 3; ++i) {
        int gct = ct0 + w * 3 + i;
        const float* bias = gct < 8 ? bq : (gct < 16 ? bk : bv);
        bfr[i] = bias[(gct & 7) * 16 + ll];
    }

    f32x4 acc[3][4];
    #pragma unroll
    for (int i = 0; i < 3; ++i)
        #pragma unroll
        for (int rf = 0; rf < 4; ++rf) acc[i][rf] = (f32x4){0.f, 0.f, 0.f, 0.f};

    #pragma unroll 1
    for (int kb = 0; kb < 4; ++kb) {
        bf16x8 xh[4], xl[4];
        #pragma unroll
        for (int rf = 0; rf < 4; ++rf) {
            float4 xa = *(const float4*)&sh.xs[rf * 16 + ll][kb * 32 + lg * 8];
            float4 xb = *(const float4*)&sh.xs[rf * 16 + ll][kb * 32 + lg * 8 + 4];
            float xv[8] = {xa.x, xa.y, xa.z, xa.w, xb.x, xb.y, xb.z, xb.w};
            #pragma unroll
            for (int j = 0; j < 8; ++j) {
                __bf16 h = (__bf16)xv[j];
                xh[rf][j] = h;
                xl[rf][j] = (__bf16)(xv[j] - (float)h);
            }
        }
        #pragma unroll
        for (int i = 0; i < 3; ++i) {
            int gct = ct0 + w * 3 + i;
            const __bf16* wb = Whg + (gct >> 3) * 16384 + ((gct & 7) * 16 + ll) * 128 + kb * 32 + lg * 8;
            const __bf16* lb = Wlg + (gct >> 3) * 16384 + ((gct & 7) * 16 + ll) * 128 + kb * 32 + lg * 8;
            bf16x8 wh = *(const bf16x8*)wb;
            bf16x8 wl = *(const bf16x8*)lb;
            #pragma unroll
            for (int rf = 0; rf < 4; ++rf) {
                acc[i][rf] = __builtin_amdgcn_mfma_f32_16x16x32_bf16(xh[rf], wh, acc[i][rf], 0, 0, 0);
                acc[i][rf] = __builtin_amdgcn_mfma_f32_16x16x32_bf16(xh[rf], wl, acc[i][rf], 0, 0, 0);
                acc[i][rf] = __builtin_amdgcn_mfma_f32_16x16x32_bf16(xl[rf], wh, acc[i][rf], 0, 0, 0);
            }
        }
    }

    __syncthreads();     // xs dead; overlay vbuf
    const float qscale = 0.08838834764831845f;  // 1/sqrt(128)
    #pragma unroll
    for (int i = 0; i < 3; ++i) {
        int gct = ct0 + w * 3 + i;
        float scale = (gct < 8) ? qscale : 1.0f;
        int lct = w * 3 + i;
        #pragma unroll
        for (int rf = 0; rf < 4; ++rf)
            #pragma unroll
            for (int r = 0; r < 4; ++r)
                sh.vbuf[rf * 16 + lg * 4 + r][lct * 16 + ll] =
                    (__bf16)((acc[i][rf][r] + bfr[i]) * scale);
    }
    __syncthreads();

    // coalesced stores per ct-chunk: Q,K row-major; V transposed
    #pragma unroll 1
    for (int lct = 0; lct < 12; ++lct) {
        int gct = ct0 + lct;
        if (gct < 16) {
            // 64 rows x 16 cols; thread t: row t>>2, 4-col chunk t&3
            int row = t >> 2, c = (t & 3) * 4;
            __bf16* base = (gct < 8 ? Q : K);
            bf16x4 v4 = *(const bf16x4*)&sh.vbuf[row][lct * 16 + c];
            *(bf16x4*)(base + (rt * 64 + row) * 128 + (gct & 7) * 16 + c) = v4;
        } else {
            // V transposed: 16 channels x 64 seq; thread t: ch t>>4, 4-seq t&15
            int e = (gct - 16) * 16 + (t >> 4);
            int s0 = (t & 15) * 4;
            int bb = rt >> 6, sb = (rt & 63) * 64 + s0;
            bf16x4 v4;
            #pragma unroll
            for (int j = 0; j < 4; ++j) v4[j] = sh.vbuf[s0 + j][lct * 16 + (t >> 4)];
            *(bf16x4*)(Vt + bb * (128 * 4096) + e * 4096 + sb) = v4;
        }
    }
}

// ---------------------------------------------------------------------------
// Kernel 2: flash attention partial (R12 anchor; Op in fp16 — R15 proven).
// DOUBLE-BUFFERED K/V, issue-early staging, one vmcnt(0)+barrier per iter.
// 2x q-row register blocking; swapped QK^T; lane-scalar softmax.
// ---------------------------------------------------------------------------
__global__ __launch_bounds__(256, 2) void attn_fwd(
    const __bf16* __restrict__ Qg,
    const __bf16* __restrict__ Kg,
    const __bf16* __restrict__ Vt,
    _Float16* __restrict__ Op, float* __restrict__ m_p, float* __restrict__ l_p,
    int kv_len)
{
    __shared__ __align__(16) __bf16 Kl[2][64][128];     // [buf][key][d], swizzled units
    __shared__ __align__(16) __bf16 Vl[2][128][64];     // [buf][d][key], swizzled
    __shared__ __align__(16) __bf16 PlT[4][2][16][64];  // [wave][h][qrow][key]

    const int t  = threadIdx.x;
    const int w  = t >> 6;
    const int l  = t & 63, lg = l >> 4, ll = l & 15;
    const int sK = ll & 7;

    // ---- XCD-aware bijective swizzle (nwg = 128*nsplit, divisible by 8) ----
    const int nwg = gridDim.x * gridDim.y;
    const int lin = blockIdx.x + gridDim.x * blockIdx.y;
    const int chunk = nwg >> 3;
    const int v = (lin & 7) * chunk + (lin >> 3);
    const int qt = v & 31;
    const int b  = (v >> 5) & 3;
    const int s  = v >> 7;

    const int qrow0 = qt * 128 + w * 32;

    // Q fragments for both 16-row groups (scale folded at qkv)
    bf16x8 qa[2][4];
    #pragma unroll
    for (int h = 0; h < 2; ++h) {
        const __bf16* qb = Qg + (b * 4096 + qrow0 + h * 16 + ll) * 128 + lg * 8;
        #pragma unroll
        for (int kb = 0; kb < 4; ++kb) qa[h][kb] = *(const bf16x8*)(qb + kb * 32);
    }

    f32x4 o[2][8];
    #pragma unroll
    for (int h = 0; h < 2; ++h)
        #pragma unroll
        for (int dt = 0; dt < 8; ++dt) o[h][dt] = (f32x4){0.f, 0.f, 0.f, 0.f};
    float m[2] = {-1e30f, -1e30f}, lsum[2] = {0.f, 0.f};

    const __bf16* kbase = Kg + ((long)b * 4096 + s * kv_len) * 128;
    const __bf16* vbase = Vt + (long)b * 128 * 4096 + s * kv_len;

    // per-lane pre-swizzled source offsets; LDS dest stays linear
    int ksrc_off[4], vsrc_off[4];
    #pragma unroll
    for (int ii = 0; ii < 4; ++ii) {
        int u = w * 256 + ii * 64 + l;               // 16B unit index, [0,1024)
        int kr = u >> 4, kc = u & 15;
        ksrc_off[ii] = kr * 128 + ((kc ^ (kr & 7)) * 8);
        int vr = u >> 3, vc = u & 7;
        vsrc_off[ii] = vr * 4096 + ((vc ^ (vr & 7)) * 8);
    }

    #define STAGE(kv, bp)                                                      \
    do {                                                                       \
        _Pragma("unroll")                                                      \
        for (int ii = 0; ii < 4; ++ii)                                         \
            GLOAD_LDS16(kbase + (long)(kv) * 128 + ksrc_off[ii],               \
                        (char*)&Kl[bp][0][0] + (w * 256 + ii * 64) * 16);      \
        _Pragma("unroll")                                                      \
        for (int ii = 0; ii < 4; ++ii)                                         \
            GLOAD_LDS16(vbase + (kv) + vsrc_off[ii],                           \
                        (char*)&Vl[bp][0][0] + (w * 256 + ii * 64) * 16);      \
    } while (0)

    STAGE(0, 0);
    asm volatile("s_waitcnt vmcnt(0)" ::: "memory");
    __syncthreads();

    const int nit = kv_len >> 6;
    int p = 0;
    for (int it = 0; it < nit; ++it) {
        // issue next tile into the other buffer NOW; wait at iter end.
        // (prior barrier => all waves done reading buf p^1)
        if (it + 1 < nit) STAGE((it + 1) * 64, p ^ 1);

        // QK^T swapped: f[h][nt][r] = S[key = nt*16+lg*4+r][qrow(h) = ll]
        f32x4 f[2][4];
        #pragma unroll
        for (int h = 0; h < 2; ++h)
            #pragma unroll
            for (int nt = 0; nt < 4; ++nt) f[h][nt] = (f32x4){0.f, 0.f, 0.f, 0.f};
        #pragma unroll
        for (int nt = 0; nt < 4; ++nt) {
            #pragma unroll
            for (int kb = 0; kb < 4; ++kb) {
                bf16x8 kf = *(const bf16x8*)&Kl[p][nt * 16 + ll][((kb * 4 + lg) ^ sK) * 8];
                f[0][nt] = __builtin_amdgcn_mfma_f32_16x16x32_bf16(kf, qa[0][kb], f[0][nt], 0, 0, 0);
                f[1][nt] = __builtin_amdgcn_mfma_f32_16x16x32_bf16(kf, qa[1][kb], f[1][nt], 0, 0, 0);
            }
        }

        // softmax per row-group (lane scalar state for q-row ll)
        float alpha[2];
        #pragma unroll
        for (int h = 0; h < 2; ++h) {
            float mx = f[h][0][0];
            #pragma unroll
            for (int nt = 0; nt < 4; ++nt)
                #pragma unroll
                for (int r = 0; r < 4; ++r) mx = fmaxf(mx, f[h][nt][r]);
            mx = fmaxf(mx, __shfl_xor(mx, 16, 64));
            mx = fmaxf(mx, __shfl_xor(mx, 32, 64));
            float mnew = fmaxf(m[h], mx);
            alpha[h] = __expf(m[h] - mnew);
            float rsum = 0.f;
            #pragma unroll
            for (int nt = 0; nt < 4; ++nt) {
                __bf16 pb[4];
                #pragma unroll
                for (int r = 0; r < 4; ++r) {
                    float e = __expf(f[h][nt][r] - mnew);
                    pb[r] = (__bf16)e;
                    rsum += (float)pb[r];   // sum bf16-rounded P: normalization cancels
                }
                uint2 u2;
                u2.x = bf16bits(pb[0]) | (bf16bits(pb[1]) << 16);
                u2.y = bf16bits(pb[2]) | (bf16bits(pb[3]) << 16);
                *(uint2*)&PlT[w][h][ll][((nt * 4 + lg) ^ (sK << 1)) * 4] = u2;
            }
            rsum += __shfl_xor(rsum, 16, 64);
            rsum += __shfl_xor(rsum, 32, 64);
            lsum[h] = lsum[h] * alpha[h] + rsum;
            m[h] = mnew;
        }
        asm volatile("s_waitcnt lgkmcnt(0)" ::: "memory");
        __builtin_amdgcn_sched_barrier(0);

        // rescale O (alpha for q-rows lg*4+r held at lanes lg*4+r)
        #pragma unroll
        for (int h = 0; h < 2; ++h) {
            float arow[4];
            #pragma unroll
            for (int r = 0; r < 4; ++r) arow[r] = __shfl(alpha[h], lg * 4 + r, 64);
            #pragma unroll
            for (int dt = 0; dt < 8; ++dt)
                #pragma unroll
                for (int r = 0; r < 4; ++r) o[h][dt][r] *= arow[r];
        }

        // PV: each V fragment feeds both row-groups
        #pragma unroll
        for (int kc = 0; kc < 2; ++kc) {
            bf16x8 pa0 = *(const bf16x8*)&PlT[w][0][ll][((kc * 4 + lg) ^ sK) * 8];
            bf16x8 pa1 = *(const bf16x8*)&PlT[w][1][ll][((kc * 4 + lg) ^ sK) * 8];
            #pragma unroll
            for (int dt = 0; dt < 8; ++dt) {
                bf16x8 vb = *(const bf16x8*)&Vl[p][dt * 16 + ll][((kc * 4 + lg) ^ sK) * 8];
                o[0][dt] = __builtin_amdgcn_mfma_f32_16x16x32_bf16(pa0, vb, o[0][dt], 0, 0, 0);
                o[1][dt] = __builtin_amdgcn_mfma_f32_16x16x32_bf16(pa1, vb, o[1][dt], 0, 0, 0);
            }
        }

        // next tile's DMA done? then flip. ONE barrier per iteration.
        asm volatile("s_waitcnt vmcnt(0)" ::: "memory");
        __syncthreads();
        p ^= 1;
    }
    #undef STAGE

    // epilogue: unnormalized partial O (fp16) + per-row (m, lsum)
    #pragma unroll
    for (int h = 0; h < 2; ++h) {
        long rowbase = (long)s * (NB * SEQ) + b * 4096 + qrow0 + h * 16;
        _Float16* op = Op + rowbase * 128;
        #pragma unroll
        for (int r = 0; r < 4; ++r)
            #pragma unroll
            for (int dt = 0; dt < 8; ++dt)
                op[(lg * 4 + r) * 128 + dt * 16 + ll] = (_Float16)o[h][dt][r];
        if (lg == 0) {
            m_p[rowbase + ll] = m[h];
            l_p[rowbase + ll] = lsum[h];
        }
    }
}

// ---------------------------------------------------------------------------
// Kernel 3: merge split-K partials (Op fp16).  grid 256 x 256 thr.
// ---------------------------------------------------------------------------
__global__ __launch_bounds__(256) void attn_merge(
    const _Float16* __restrict__ Op, const float* __restrict__ m_p,
    const float* __restrict__ l_p, float* __restrict__ out, int nsplit)
{
    const int t = threadIdx.x;
    const int base_row = blockIdx.x * 64;
    #pragma unroll 1
    for (int k = 0; k < 8; ++k) {
        int u = t + k * 256;                 // float4 unit within 64x128 tile
        int row = base_row + (u >> 5);
        int dq = u & 31;
        float M = -1e30f;
        for (int sp = 0; sp < nsplit; ++sp)
            M = fmaxf(M, m_p[(long)sp * (NB * SEQ) + row]);
        float L = 0.f;
        float4 acc = {0.f, 0.f, 0.f, 0.f};
        for (int sp = 0; sp < nsplit; ++sp) {
            long rb2 = (long)sp * (NB * SEQ) + row;
            float a = __expf(m_p[rb2] - M);
            L += l_p[rb2] * a;
            f16x4 vv = *(const f16x4*)(Op + rb2 * 128 + dq * 4);
            acc.x += (float)vv[0] * a; acc.y += (float)vv[1] * a;
            acc.z += (float)vv[2] * a; acc.w += (float)vv[3] * a;
        }
        float inv = 1.f / L;
        float4 r4 = {acc.x * inv, acc.y * inv, acc.z * inv, acc.w * inv};
        *(float4*)(out + (long)row * 128 + dq * 4) = r4;
    }
}

extern "C" void kernel_launch(void* const* d_in, const int* in_sizes, int n_in,
                              void* d_out, int out_size, void* d_ws, size_t ws_size,
                              hipStream_t stream) {
    (void)in_sizes; (void)n_in; (void)out_size;
    const float* x  = (const float*)d_in[0];
    const float* Wq = (const float*)d_in[1];
    const float* bq = (const float*)d_in[2];
    const float* Wk = (const float*)d_in[3];
    const float* bk = (const float*)d_in[4];
    const float* Wv = (const float*)d_in[5];
    const float* bv = (const float*)d_in[6];
    float* out = (float*)d_out;

    const size_t qkv_elems = (size_t)NB * SEQ * DIM;          // 2 MB elems
    char* p = (char*)d_ws;
    __bf16* Q  = (__bf16*)p;        p += qkv_elems * 2;       // 4 MB
    __bf16* K  = (__bf16*)p;        p += qkv_elems * 2;       // 4 MB
    __bf16* Vt = (__bf16*)p;        p += qkv_elems * 2;       // 4 MB
    __bf16* Wh = (__bf16*)p;        p += 3 * DIM * DIM * 2;   // 96 KB
    __bf16* Wl = (__bf16*)p;        p += 3 * DIM * DIM * 2;   // 96 KB
    size_t used = (size_t)(p - (char*)d_ws);

    // partials: per split 4 MB O (fp16) + 64 KB m + 64 KB l
    const size_t per_split = (size_t)NB * SEQ * DIM * 2 + 2 * (size_t)NB * SEQ * 4;
    int nsplit = 4;
    while (nsplit > 1 && used + (size_t)nsplit * per_split > ws_size) nsplit >>= 1;

    _Float16* Op = (_Float16*)p;                 p += (size_t)nsplit * NB * SEQ * DIM * 2;
    float* m_p = (float*)p;                      p += (size_t)nsplit * NB * SEQ * 4;
    float* l_p = (float*)p;

    wconv<<<48, 256, 0, stream>>>(Wq, Wk, Wv, Wh, Wl);
    dim3 g1(256, 2);
    qkv_proj3<<<g1, 256, 0, stream>>>(x, Wh, Wl, bq, bk, bv, Q, K, Vt);
    dim3 g2(128, nsplit);
    attn_fwd<<<g2, 256, 0, stream>>>(Q, K, Vt, Op, m_p, l_p, SEQ / nsplit);
    attn_merge<<<256, 256, 0, stream>>>(Op, m_p, l_p, out, nsplit);
}

// Round 17
// 88.453 us; speedup vs baseline: 1.2217x; 1.0563x over previous
//
#include <hip/hip_runtime.h>
#include <hip/hip_bf16.h>

typedef __bf16 bf16x8 __attribute__((ext_vector_type(8)));
typedef __bf16 bf16x4 __attribute__((ext_vector_type(4)));
typedef float  f32x4  __attribute__((ext_vector_type(4)));
typedef float  f32x16 __attribute__((ext_vector_type(16)));
typedef _Float16 f16x4 __attribute__((ext_vector_type(4)));

#define NB 4
#define SEQ 4096
#define DIM 128

static __device__ __forceinline__ unsigned int bf16bits(__bf16 h) {
    return (unsigned int)__builtin_bit_cast(unsigned short, h);
}

// global -> LDS direct copy, 16B per lane; LDS dest is wave-uniform base,
// HW writes lane i at base + i*16 (m104). Global src is per-lane (m173).
#define GLOAD_LDS16(g, s) __builtin_amdgcn_global_load_lds(                    \
    (const __attribute__((address_space(1))) void*)(g),                        \
    (__attribute__((address_space(3))) void*)(s), 16, 0, 0)

// ---------------------------------------------------------------------------
// Kernel 0: W fp32 -> (Wh, Wl) bf16 split pair.  Wh = bf16(w), Wl = bf16(w-Wh)
// ---------------------------------------------------------------------------
__global__ __launch_bounds__(256) void wconv(
    const float* __restrict__ Wq, const float* __restrict__ Wk,
    const float* __restrict__ Wv,
    __bf16* __restrict__ Wh, __bf16* __restrict__ Wl)
{
    int idx = blockIdx.x * 256 + threadIdx.x;     // float4 index, 12288 total
    int which = idx >> 12;                        // 4096 float4 per matrix
    int off = (idx & 4095) * 4;
    const float* W = which == 0 ? Wq : (which == 1 ? Wk : Wv);
    float4 v = *(const float4*)(W + off);
    bf16x4 h, lo;
    h[0] = (__bf16)v.x; h[1] = (__bf16)v.y; h[2] = (__bf16)v.z; h[3] = (__bf16)v.w;
    lo[0] = (__bf16)(v.x - (float)h[0]);
    lo[1] = (__bf16)(v.y - (float)h[1]);
    lo[2] = (__bf16)(v.z - (float)h[2]);
    lo[3] = (__bf16)(v.w - (float)h[3]);
    *(bf16x4*)(Wh + which * 16384 + off) = h;
    *(bf16x4*)(Wl + which * 16384 + off) = lo;
}

// ---------------------------------------------------------------------------
// Kernel 1 (R14 verbatim): FUSED QKV projection, ct-split across blockIdx.y.
// ---------------------------------------------------------------------------
union QkvSh {
    float  xs[64][132];              // 33.8 KB, padded: conflict-free b128
    __bf16 vbuf[64][200];            // 25.6 KB: 12 cts x 16 cols + 8 pad
};

__global__ __launch_bounds__(256) void qkv_proj3(
    const float* __restrict__ x,
    const __bf16* __restrict__ Whg, const __bf16* __restrict__ Wlg,
    const float* __restrict__ bq, const float* __restrict__ bk,
    const float* __restrict__ bv,
    __bf16* __restrict__ Q, __bf16* __restrict__ K, __bf16* __restrict__ Vt)
{
    __shared__ QkvSh sh;
    const int t  = threadIdx.x;
    const int w  = t >> 6, l = t & 63, lg = l >> 4, ll = l & 15;
    const int rt = blockIdx.x;
    const int ct0 = blockIdx.y * 12;           // 0 or 12

    // stage x tile 64x128 -> padded LDS (2048 float4)
    {
        const float4* xsrc = (const float4*)(x + rt * 64 * 128);
        #pragma unroll
        for (int ii = 0; ii < 8; ++ii) {
            int u = t + ii * 256;              // row = u>>5, c4 = u&31
            float4 v4 = xsrc[u];
            *(float4*)&sh.xs[u >> 5][(u & 31) * 4] = v4;
        }
    }
    __syncthreads();

    float bfr[3];
    #pragma unroll
    for (int i = 0; i < 3; ++i) {
        int gct = ct0 + w * 3 + i;
        const float* bias = gct < 8 ? bq : (gct < 16 ? bk : bv);
        bfr[i] = bias[(gct & 7) * 16 + ll];
    }

    f32x4 acc[3][4];
    #pragma unroll
    for (int i = 0; i < 3; ++i)
        #pragma unroll
        for (int rf = 0; rf < 4; ++rf) acc[i][rf] = (f32x4){0.f, 0.f, 0.f, 0.f};

    #pragma unroll 1
    for (int kb = 0; kb < 4; ++kb) {
        bf16x8 xh[4], xl[4];
        #pragma unroll
        for (int rf = 0; rf < 4; ++rf) {
            float4 xa = *(const float4*)&sh.xs[rf * 16 + ll][kb * 32 + lg * 8];
            float4 xb = *(const float4*)&sh.xs[rf * 16 + ll][kb * 32 + lg * 8 + 4];
            float xv[8] = {xa.x, xa.y, xa.z, xa.w, xb.x, xb.y, xb.z, xb.w};
            #pragma unroll
            for (int j = 0; j < 8; ++j) {
                __bf16 h = (__bf16)xv[j];
                xh[rf][j] = h;
                xl[rf][j] = (__bf16)(xv[j] - (float)h);
            }
        }
        #pragma unroll
        for (int i = 0; i < 3; ++i) {
            int gct = ct0 + w * 3 + i;
            const __bf16* wb = Whg + (gct >> 3) * 16384 + ((gct & 7) * 16 + ll) * 128 + kb * 32 + lg * 8;
            const __bf16* lb = Wlg + (gct >> 3) * 16384 + ((gct & 7) * 16 + ll) * 128 + kb * 32 + lg * 8;
            bf16x8 wh = *(const bf16x8*)wb;
            bf16x8 wl = *(const bf16x8*)lb;
            #pragma unroll
            for (int rf = 0; rf < 4; ++rf) {
                acc[i][rf] = __builtin_amdgcn_mfma_f32_16x16x32_bf16(xh[rf], wh, acc[i][rf], 0, 0, 0);
                acc[i][rf] = __builtin_amdgcn_mfma_f32_16x16x32_bf16(xh[rf], wl, acc[i][rf], 0, 0, 0);
                acc[i][rf] = __builtin_amdgcn_mfma_f32_16x16x32_bf16(xl[rf], wh, acc[i][rf], 0, 0, 0);
            }
        }
    }

    __syncthreads();     // xs dead; overlay vbuf
    const float qscale = 0.08838834764831845f;  // 1/sqrt(128)
    #pragma unroll
    for (int i = 0; i < 3; ++i) {
        int gct = ct0 + w * 3 + i;
        float scale = (gct < 8) ? qscale : 1.0f;
        int lct = w * 3 + i;
        #pragma unroll
        for (int rf = 0; rf < 4; ++rf)
            #pragma unroll
            for (int r = 0; r < 4; ++r)
                sh.vbuf[rf * 16 + lg * 4 + r][lct * 16 + ll] =
                    (__bf16)((acc[i][rf][r] + bfr[i]) * scale);
    }
    __syncthreads();

    // coalesced stores per ct-chunk: Q,K row-major; V transposed
    #pragma unroll 1
    for (int lct = 0; lct < 12; ++lct) {
        int gct = ct0 + lct;
        if (gct < 16) {
            int row = t >> 2, c = (t & 3) * 4;
            __bf16* base = (gct < 8 ? Q : K);
            bf16x4 v4 = *(const bf16x4*)&sh.vbuf[row][lct * 16 + c];
            *(bf16x4*)(base + (rt * 64 + row) * 128 + (gct & 7) * 16 + c) = v4;
        } else {
            int e = (gct - 16) * 16 + (t >> 4);
            int s0 = (t & 15) * 4;
            int bb = rt >> 6, sb = (rt & 63) * 64 + s0;
            bf16x4 v4;
            #pragma unroll
            for (int j = 0; j < 4; ++j) v4[j] = sh.vbuf[s0 + j][lct * 16 + (t >> 4)];
            *(bf16x4*)(Vt + bb * (128 * 4096) + e * 4096 + sb) = v4;
        }
    }
}

// ---------------------------------------------------------------------------
// Kernel 2 (R17): flash attention partial on 32x32 MFMA, in-register P.
// Swapped QK^T: f = mfma(K, Q) -> lane (q=l&31, hi=l>>5) holds
//   S[key = (r&3)+8*(r>>2)+4*hi + 32*kb32][q]  (C/D layout m74/m101).
// Softmax state per-lane scalar for q; O kept TRANSPOSED (O^T = mfma(V^T,P^T))
// so rescale is lane-local. P exchanged in-register via v_permlane32_swap.
// R12 shell: dbuf K/V, issue-early STAGE, one vmcnt(0)+barrier per iter.
// LDS 64 KB -> 2 blocks/CU. Block 256 thr = 4 waves x 32 q-rows.
// ---------------------------------------------------------------------------
__global__ __launch_bounds__(256, 2) void attn_fwd(
    const __bf16* __restrict__ Qg,
    const __bf16* __restrict__ Kg,
    const __bf16* __restrict__ Vt,
    _Float16* __restrict__ Op, float* __restrict__ m_p, float* __restrict__ l_p,
    int kv_len)
{
    __shared__ __align__(16) __bf16 Kl[2][64][128];     // [buf][key][d], swizzled units
    __shared__ __align__(16) __bf16 Vl[2][128][64];     // [buf][d][key], swizzled

    const int t  = threadIdx.x;
    const int w  = t >> 6;
    const int l  = t & 63;
    const int q  = l & 31;       // lane's q-column
    const int hi = l >> 5;
    const int s8 = l & 7;        // read-side swizzle (= row&7 for all our reads)

    // ---- XCD-aware bijective swizzle (nwg = 128*nsplit, divisible by 8) ----
    const int nwg = gridDim.x * gridDim.y;
    const int lin = blockIdx.x + gridDim.x * blockIdx.y;
    const int chunk = nwg >> 3;
    const int v = (lin & 7) * chunk + (lin >> 3);
    const int qt = v & 31;
    const int b  = (v >> 5) & 3;
    const int s  = v >> 7;

    const int qrow0 = qt * 128 + w * 32;

    // Q B-fragments: col=q, k=hi*8+j; 8 k-steps of 16 (scale folded at qkv)
    bf16x8 qf[8];
    {
        const __bf16* qb = Qg + ((long)b * 4096 + qrow0 + q) * 128 + hi * 8;
        #pragma unroll
        for (int ks = 0; ks < 8; ++ks) qf[ks] = *(const bf16x8*)(qb + ks * 16);
    }

    f32x16 o32[4];
    #pragma unroll
    for (int dblk = 0; dblk < 4; ++dblk)
        #pragma unroll
        for (int r = 0; r < 16; ++r) o32[dblk][r] = 0.f;
    float m = -1e30f, lsum = 0.f;

    const __bf16* kbase = Kg + ((long)b * 4096 + s * kv_len) * 128;
    const __bf16* vbase = Vt + (long)b * 128 * 4096 + s * kv_len;

    // per-lane pre-swizzled source offsets; LDS dest stays linear
    int ksrc_off[4], vsrc_off[4];
    #pragma unroll
    for (int ii = 0; ii < 4; ++ii) {
        int u = w * 256 + ii * 64 + l;               // 16B unit index, [0,1024)
        int kr = u >> 4, kc = u & 15;
        ksrc_off[ii] = kr * 128 + ((kc ^ (kr & 7)) * 8);
        int vr = u >> 3, vc = u & 7;
        vsrc_off[ii] = vr * 4096 + ((vc ^ (vr & 7)) * 8);
    }

    #define STAGE(kv, bp)                                                      \
    do {                                                                       \
        _Pragma("unroll")                                                      \
        for (int ii = 0; ii < 4; ++ii)                                         \
            GLOAD_LDS16(kbase + (long)(kv) * 128 + ksrc_off[ii],               \
                        (char*)&Kl[bp][0][0] + (w * 256 + ii * 64) * 16);      \
        _Pragma("unroll")                                                      \
        for (int ii = 0; ii < 4; ++ii)                                         \
            GLOAD_LDS16(vbase + (kv) + vsrc_off[ii],                           \
                        (char*)&Vl[bp][0][0] + (w * 256 + ii * 64) * 16);      \
    } while (0)

    STAGE(0, 0);
    asm volatile("s_waitcnt vmcnt(0)" ::: "memory");
    __syncthreads();

    const int nit = kv_len >> 6;
    int p = 0;
    for (int it = 0; it < nit; ++it) {
        if (it + 1 < nit) STAGE((it + 1) * 64, p ^ 1);

        // QK^T: f0 = keys 0..31, f1 = keys 32..63 (this lane: 16 each)
        f32x16 f0, f1;
        #pragma unroll
        for (int r = 0; r < 16; ++r) { f0[r] = 0.f; f1[r] = 0.f; }
        #pragma unroll
        for (int ks = 0; ks < 8; ++ks) {
            bf16x8 k0 = *(const bf16x8*)&Kl[p][q]     [(((ks * 2 + hi) ^ s8)) * 8];
            bf16x8 k1 = *(const bf16x8*)&Kl[p][32 + q][(((ks * 2 + hi) ^ s8)) * 8];
            f0 = __builtin_amdgcn_mfma_f32_32x32x16_bf16(k0, qf[ks], f0, 0, 0, 0);
            f1 = __builtin_amdgcn_mfma_f32_32x32x16_bf16(k1, qf[ks], f1, 0, 0, 0);
        }

        // softmax: lane-local for q; only ONE cross-lane shfl (hi-halves)
        float mx = f0[0];
        #pragma unroll
        for (int r = 1; r < 16; ++r) mx = fmaxf(mx, f0[r]);
        #pragma unroll
        for (int r = 0; r < 16; ++r) mx = fmaxf(mx, f1[r]);
        mx = fmaxf(mx, __shfl_xor(mx, 32, 64));
        float mnew = fmaxf(m, mx);
        float alpha = __expf(m - mnew);
        m = mnew;

        // P = exp(f - m), bf16-rounded; rsum over rounded values
        float rsum = 0.f;
        unsigned int d0[8], d1[8];
        #pragma unroll
        for (int G = 0; G < 8; ++G) {
            int base = (G & 3) * 4;
            float pv[4];
            #pragma unroll
            for (int c = 0; c < 4; ++c) {
                float fv = (G >> 2) ? f1[base + c] : f0[base + c];
                pv[c] = __expf(fv - mnew);
            }
            __bf16 pb[4];
            #pragma unroll
            for (int c = 0; c < 4; ++c) { pb[c] = (__bf16)pv[c]; rsum += (float)pb[c]; }
            d0[G] = bf16bits(pb[0]) | (bf16bits(pb[1]) << 16);
            d1[G] = bf16bits(pb[2]) | (bf16bits(pb[3]) << 16);
        }
        lsum = lsum * alpha + rsum;

        // rescale O^T: lane-local (alpha is this lane's q)
        #pragma unroll
        for (int dblk = 0; dblk < 4; ++dblk)
            #pragma unroll
            for (int r = 0; r < 16; ++r) o32[dblk][r] *= alpha;

        // exchange P across hi-halves -> B-fragments P^T[key][q]
        // frag[k]: keys 16k+8*hi+j; dw0,dw2 <- swap(d0[2k],d0[2k+1]);
        //          dw1,dw3 <- swap(d1[2k],d1[2k+1])
        bf16x8 pf[4];
        #pragma unroll
        for (int k = 0; k < 4; ++k) {
            unsigned int a0 = d0[2 * k], b0 = d0[2 * k + 1];
            unsigned int a1 = d1[2 * k], b1 = d1[2 * k + 1];
            asm volatile("v_permlane32_swap_b32 %0, %1" : "+v"(a0), "+v"(b0));
            asm volatile("v_permlane32_swap_b32 %0, %1" : "+v"(a1), "+v"(b1));
            unsigned int dw[4] = {a0, a1, b0, b1};
            pf[k] = __builtin_bit_cast(bf16x8, *(uint4*)dw);
        }

        // PV: O^T[d][q] += V^T-frag x P^T-frag  (16 MFMAs)
        #pragma unroll
        for (int k = 0; k < 4; ++k) {
            #pragma unroll
            for (int dblk = 0; dblk < 4; ++dblk) {
                bf16x8 vf = *(const bf16x8*)&Vl[p][dblk * 32 + q][(((k * 2 + hi) ^ s8)) * 8];
                o32[dblk] = __builtin_amdgcn_mfma_f32_32x32x16_bf16(vf, pf[k], o32[dblk], 0, 0, 0);
            }
        }

        asm volatile("s_waitcnt vmcnt(0)" ::: "memory");
        __syncthreads();
        p ^= 1;
    }
    #undef STAGE

    // epilogue: O^T -> Op[row][d] (fp16 scattered stores; L2 aggregates),
    // per-row (m, lsum)
    long rowg = (long)s * (NB * SEQ) + b * 4096 + qrow0 + q;
    _Float16* op = Op + rowg * 128;
    #pragma unroll
    for (int dblk = 0; dblk < 4; ++dblk)
        #pragma unroll
        for (int d2 = 0; d2 < 4; ++d2)
            #pragma unroll
            for (int c = 0; c < 4; ++c)
                op[dblk * 32 + d2 * 8 + hi * 4 + c] = (_Float16)o32[dblk][d2 * 4 + c];
    lsum += __shfl_xor(lsum, 32, 64);
    if (hi == 0) {
        m_p[rowg] = m;
        l_p[rowg] = lsum;
    }
}

// ---------------------------------------------------------------------------
// Kernel 3: merge split-K partials (Op fp16).  grid 256 x 256 thr.
// ---------------------------------------------------------------------------
__global__ __launch_bounds__(256) void attn_merge(
    const _Float16* __restrict__ Op, const float* __restrict__ m_p,
    const float* __restrict__ l_p, float* __restrict__ out, int nsplit)
{
    const int t = threadIdx.x;
    const int base_row = blockIdx.x * 64;
    #pragma unroll 1
    for (int k = 0; k < 8; ++k) {
        int u = t + k * 256;                 // float4 unit within 64x128 tile
        int row = base_row + (u >> 5);
        int dq = u & 31;
        float M = -1e30f;
        for (int sp = 0; sp < nsplit; ++sp)
            M = fmaxf(M, m_p[(long)sp * (NB * SEQ) + row]);
        float L = 0.f;
        float4 acc = {0.f, 0.f, 0.f, 0.f};
        for (int sp = 0; sp < nsplit; ++sp) {
            long rb2 = (long)sp * (NB * SEQ) + row;
            float a = __expf(m_p[rb2] - M);
            L += l_p[rb2] * a;
            f16x4 vv = *(const f16x4*)(Op + rb2 * 128 + dq * 4);
            acc.x += (float)vv[0] * a; acc.y += (float)vv[1] * a;
            acc.z += (float)vv[2] * a; acc.w += (float)vv[3] * a;
        }
        float inv = 1.f / L;
        float4 r4 = {acc.x * inv, acc.y * inv, acc.z * inv, acc.w * inv};
        *(float4*)(out + (long)row * 128 + dq * 4) = r4;
    }
}

extern "C" void kernel_launch(void* const* d_in, const int* in_sizes, int n_in,
                              void* d_out, int out_size, void* d_ws, size_t ws_size,
                              hipStream_t stream) {
    (void)in_sizes; (void)n_in; (void)out_size;
    const float* x  = (const float*)d_in[0];
    const float* Wq = (const float*)d_in[1];
    const float* bq = (const float*)d_in[2];
    const float* Wk = (const float*)d_in[3];
    const float* bk = (const float*)d_in[4];
    const float* Wv = (const float*)d_in[5];
    const float* bv = (const float*)d_in[6];
    float* out = (float*)d_out;

    const size_t qkv_elems = (size_t)NB * SEQ * DIM;          // 2 MB elems
    char* p = (char*)d_ws;
    __bf16* Q  = (__bf16*)p;        p += qkv_elems * 2;       // 4 MB
    __bf16* K  = (__bf16*)p;        p += qkv_elems * 2;       // 4 MB
    __bf16* Vt = (__bf16*)p;        p += qkv_elems * 2;       // 4 MB
    __bf16* Wh = (__bf16*)p;        p += 3 * DIM * DIM * 2;   // 96 KB
    __bf16* Wl = (__bf16*)p;        p += 3 * DIM * DIM * 2;   // 96 KB
    size_t used = (size_t)(p - (char*)d_ws);

    // partials: per split 4 MB O (fp16) + 64 KB m + 64 KB l
    const size_t per_split = (size_t)NB * SEQ * DIM * 2 + 2 * (size_t)NB * SEQ * 4;
    int nsplit = 4;
    while (nsplit > 1 && used + (size_t)nsplit * per_split > ws_size) nsplit >>= 1;

    _Float16* Op = (_Float16*)p;                 p += (size_t)nsplit * NB * SEQ * DIM * 2;
    float* m_p = (float*)p;                      p += (size_t)nsplit * NB * SEQ * 4;
    float* l_p = (float*)p;

    wconv<<<48, 256, 0, stream>>>(Wq, Wk, Wv, Wh, Wl);
    dim3 g1(256, 2);
    qkv_proj3<<<g1, 256, 0, stream>>>(x, Wh, Wl, bq, bk, bv, Q, K, Vt);
    dim3 g2(128, nsplit);
    attn_fwd<<<g2, 256, 0, stream>>>(Q, K, Vt, Op, m_p, l_p, SEQ / nsplit);
    attn_merge<<<256, 256, 0, stream>>>(Op, m_p, l_p, out, nsplit);
}